// Round 16
// baseline (359.571 us; speedup 1.0000x reference)
//
#include <hip/hip_runtime.h>
#include <hip/hip_bf16.h>

typedef __bf16 bf16x8 __attribute__((ext_vector_type(8)));
typedef float f32x4 __attribute__((ext_vector_type(4)));
typedef float f32x16 __attribute__((ext_vector_type(16)));

// B=2, T=2048, d=768, h=8
#define SCALE 0.03608439182435161f   // 1/sqrt(768)
#define NEGINF (-1e30f)

static __device__ __forceinline__ ushort f2bf(float f) {
    union { float f; unsigned u; } v; v.f = f;
    unsigned r = (v.u + 0x7fff + ((v.u >> 16) & 1)) >> 16;  // RTE
    return (ushort)r;
}
static __device__ __forceinline__ float bf2f(ushort u) {
    union { unsigned u; float f; } v; v.u = ((unsigned)u) << 16;
    return v.f;
}

// async 16B global -> LDS (dest: wave-uniform base + lane*16)
static __device__ __forceinline__ void gload16(const void* g, void* lds) {
    __builtin_amdgcn_global_load_lds((const __attribute__((address_space(1))) void*)g,
                                     (__attribute__((address_space(3))) void*)lds, 16, 0, 0);
}

// ALL barriers fenced: raw s_barrier is NOT a compiler memory fence (R9 lesson).
#define PHASEB do { asm volatile("s_waitcnt vmcnt(0) lgkmcnt(0)" ::: "memory"); \
                    __builtin_amdgcn_s_barrier(); \
                    asm volatile("" ::: "memory"); } while (0)
#define BARL do { asm volatile("s_waitcnt lgkmcnt(0)" ::: "memory"); \
                  __builtin_amdgcn_s_barrier(); \
                  asm volatile("" ::: "memory"); } while (0)

// ---------------- f32 -> bf16 convert (x) ----------------
__global__ void k_convx(const float* __restrict__ x, ushort* __restrict__ xb, int n4) {
    int i = blockIdx.x * blockDim.x + threadIdx.x;
    if (i >= n4) return;
    float4 v = ((const float4*)x)[i];
    ushort4 o; o.x = f2bf(v.x); o.y = f2bf(v.y); o.z = f2bf(v.z); o.w = f2bf(v.w);
    ((ushort4*)xb)[i] = o;
}

// ---------------- fused transpose-convert: z=0 M->Mt, z=1 V->Vt (768x6144 -> [6144][768]) ----------------
__global__ void k_tconv2(const float* __restrict__ M, const float* __restrict__ V,
                         ushort* __restrict__ Mt, ushort* __restrict__ Vt) {
    __shared__ float ts[32][33];
    const float* in = blockIdx.z ? V : M;
    ushort* out = blockIdx.z ? Vt : Mt;
    int r0 = blockIdx.x * 32, c0 = blockIdx.y * 32;
    int lr = threadIdx.x >> 5, lc = threadIdx.x & 31;
#pragma unroll
    for (int i = 0; i < 4; i++) ts[lr + i * 8][lc] = in[(r0 + lr + i * 8) * 6144 + c0 + lc];
    __syncthreads();
#pragma unroll
    for (int i = 0; i < 4; i++) out[(c0 + lr + i * 8) * 768 + r0 + lc] = f2bf(ts[lc][lr + i * 8]);
}

// ---------------- fused bf16 GEMMs (m97-style, R14 staging) ----------------
// z=0: Qr[b][h][t][dd] = xb * Mt^T   (M=4096 rows, N=6144 cols)
// z=1: valT[b][h][dd][t] = Vt * xb^T (M=6144 rows, N=4096 cols)
__global__ __launch_bounds__(256) void k_gemmc(const ushort* __restrict__ xb,
                                               const ushort* __restrict__ Mt,
                                               const ushort* __restrict__ Vt,
                                               ushort* __restrict__ Qr,
                                               ushort* __restrict__ valT) {
    __shared__ ushort As[128 * 32];
    __shared__ ushort Bs[128 * 32];
    const int z = blockIdx.z;
    const ushort* A  = z ? Vt : xb;
    const ushort* Bt = z ? xb : Mt;
    ushort* out = z ? valT : Qr;
    const int mt = z ? 48 : 32;
    const int wg = blockIdx.x;
    const int m0 = (wg % mt) * 128, n0 = (wg / mt) * 128;

    const int tid = threadIdx.x, lane = tid & 63, wid = tid >> 6;
    const int wm = (wid >> 1) * 64, wn = (wid & 1) * 64;
    const int l15 = lane & 15, l4 = lane >> 4;
    const int srow = tid >> 2, scol = (tid & 3) * 8;
    f32x4 acc[4][4] = {};

    for (int kt = 0; kt < 768; kt += 32) {
        gload16(&A[(size_t)(m0 + srow) * 768 + kt + scol],       (char*)As + wid * 1024);
        gload16(&A[(size_t)(m0 + 64 + srow) * 768 + kt + scol],  (char*)As + 4096 + wid * 1024);
        gload16(&Bt[(size_t)(n0 + srow) * 768 + kt + scol],      (char*)Bs + wid * 1024);
        gload16(&Bt[(size_t)(n0 + 64 + srow) * 768 + kt + scol], (char*)Bs + 4096 + wid * 1024);
        PHASEB;
        bf16x8 af[4], bfr[4];
#pragma unroll
        for (int m = 0; m < 4; m++)
            af[m] = *(const bf16x8*)&As[(wm + m * 16 + l15) * 32 + l4 * 8];
#pragma unroll
        for (int n = 0; n < 4; n++)
            bfr[n] = *(const bf16x8*)&Bs[(wn + n * 16 + l15) * 32 + l4 * 8];
#pragma unroll
        for (int m = 0; m < 4; m++)
#pragma unroll
            for (int n = 0; n < 4; n++)
                acc[m][n] = __builtin_amdgcn_mfma_f32_16x16x32_bf16(af[m], bfr[n], acc[m][n], 0, 0, 0);
        BARL;
    }

#pragma unroll
    for (int m = 0; m < 4; m++) {
#pragma unroll
        for (int n = 0; n < 4; n++) {
#pragma unroll
            for (int r = 0; r < 4; r++) {
                int row = m0 + wm + m * 16 + l4 * 4 + r;
                int col = n0 + wn + n * 16 + l15;
                float v = acc[m][n][r];
                int idx;
                if (z == 0) {
                    int b = row >> 11, t = row & 2047;
                    int hh = col / 768, dd = col - hh * 768;
                    idx = ((b * 8 + hh) * 2048 + t) * 768 + dd;
                } else {
                    int hh = row / 768, dd = row - hh * 768;
                    int b = col >> 11, t = col & 2047;
                    idx = ((b * 8 + hh) * 768 + dd) * 2048 + t;
                }
                out[idx] = f2bf(v);
            }
        }
    }
}

// ---------------- RoPE(x) -> Kr bf16 (layout [b][t][768]); also emits cos/sin table ----------------
// tab[t][j] = (cos(ang)*SCALE, sin(ang)*SCALE), j in [0,384), written by b==0 rows.
__global__ void k_ropek(const float* __restrict__ x, ushort* __restrict__ Kr,
                        const int* __restrict__ pos, float2* __restrict__ tab, int nrows) {
    int i = blockIdx.x * blockDim.x + threadIdx.x;
    int row = i / 96, j4 = (i % 96) * 4;
    if (row >= nrows) return;
    float p = (float)pos[row & 2047];
    float4 x1 = *(const float4*)&x[row * 768 + j4];
    float4 x2 = *(const float4*)&x[row * 768 + 384 + j4];
    ushort4 o1, o2;
    float a1[4] = {x1.x, x1.y, x1.z, x1.w};
    float a2[4] = {x2.x, x2.y, x2.z, x2.w};
#pragma unroll
    for (int k = 0; k < 4; k++) {
        float inv = exp2f(-(float)(j4 + k) * (13.287712379549449f / 384.0f));
        float ang = p * inv;
        float s, c; sincosf(ang, &s, &c);
        ((ushort*)&o1)[k] = f2bf(a1[k] * c - a2[k] * s);
        ((ushort*)&o2)[k] = f2bf(a1[k] * s + a2[k] * c);
        if (row < 2048) tab[(size_t)row * 384 + j4 + k] = make_float2(c * SCALE, s * SCALE);
    }
    *(ushort4*)&Kr[row * 768 + j4] = o1;
    *(ushort4*)&Kr[row * 768 + 384 + j4] = o2;
}

// ---------------- Flash attention v14 (unchanged from R14) ----------------
__global__ __launch_bounds__(512, 2) void k_attn(const ushort* Qr, const ushort* __restrict__ Kr,
                                                 const ushort* __restrict__ valT,
                                                 const float2* __restrict__ tab, ushort* Oh) {
    __shared__ alignas(128) char Qs[98304];     // [6][64 q][128 d] bf16, 16-deep XOR swizzle
    __shared__ alignas(128) char pool[65536];   // 2 x 32KB stream slots

    const int p = blockIdx.x, hh = blockIdx.y, b = blockIdx.z;
    const int bh = b * 8 + hh;
    const int tid = threadIdx.x, lane = tid & 63, wid = tid >> 6;
    const int g = wid & 3, qh = wid >> 2;       // k-tile / q-half roles
    const int l31 = lane & 31, hi = lane >> 5;
    const int hi16 = hi << 4;

    // staging geometry: chunk = [128 rows][256B], dest linear = tid*16 per 8KB round
    const int row0 = tid >> 4, col16 = tid & 15;
    const int swz = (col16 << 4) ^ ((row0 & 15) << 4);   // pre-swizzled source column

    const int arow = g * 32 + l31;              // K row (QK A) / V dd-row (PV B)
    const int qrow = qh * 32 + l31;             // Q row (QK B) / lane's q
    const int asw = (arow & 15) << 4;
    const int qsw = (qrow & 15) << 4;

    char* Pb = pool + 32768;                    // P [64 q][128 k] bf16 (slot1 overlay)
    float* pmax_s = (float*)(pool + 49152);     // [64][4] — disjoint from P
    float* psum_s = (float*)(pool + 50176);     // [64][4]

    const char* Kb0 = (const char*)Kr + ((size_t)(b * 2048 + row0)) * 1536 + swz;
    const char* Vb0 = (const char*)valT + ((size_t)(bh * 768 + row0)) * 4096 + swz;

    for (int ti = 0; ti < 2; ti++) {
        const int qt = ti ? (31 - p) : p;
        const int q0 = qt * 64;
        const int nkb = (qt + 2) >> 1;
        const int qg = q0 + qrow;

        // prologue: issue Q (6 chunks, 12 rounds) + K0 -> slot0
        const char* qsrc = (const char*)Qr + ((size_t)(bh * 2048 + q0 + row0)) * 1536 + swz;
#pragma unroll
        for (int r = 0; r < 12; r++)
            gload16(qsrc + (r >> 1) * 256 + (size_t)(r & 1) * 49152,
                    Qs + (r >> 1) * 16384 + (r & 1) * 8192 + wid * 1024);
#pragma unroll
        for (int r = 0; r < 4; r++)
            gload16(Kb0 + (size_t)r * 49152, pool + r * 8192 + wid * 1024);

        PHASEB;   // Q (and K0) landed block-wide

        // ---- fused RoPE+SCALE on Q, in LDS (table-based) ----
        // pair (d, d+384) lives in chunks (c, c+3) at the same row/byte offset.
        {
            const int rr = tid >> 3;                 // 0..63 (q row in tile)
            const int gb0 = (tid & 7) * 16;          // granule byte base
            const int rsw = (rr & 15) << 4;
            const float2* trow = tab + (size_t)(q0 + rr) * 384 + (gb0 >> 1);
#pragma unroll
            for (int c = 0; c < 3; c++) {
#pragma unroll
                for (int h2 = 0; h2 < 2; h2++) {
                    int gb = gb0 + h2 * 128;
                    char* p1 = Qs + c * 16384 + rr * 256 + (gb ^ rsw);
                    char* p2 = Qs + (c + 3) * 16384 + rr * 256 + (gb ^ rsw);
                    uint4 u1 = *(uint4*)p1, u2 = *(uint4*)p2;
                    const float4* tp = (const float4*)(trow + c * 128 + h2 * 64);
                    float4 T0 = tp[0], T1 = tp[1], T2 = tp[2], T3 = tp[3];
                    const float tf[16] = {T0.x, T0.y, T0.z, T0.w, T1.x, T1.y, T1.z, T1.w,
                                          T2.x, T2.y, T2.z, T2.w, T3.x, T3.y, T3.z, T3.w};
                    uint4 o1, o2;
                    ushort* a1 = (ushort*)&u1; ushort* a2 = (ushort*)&u2;
                    ushort* b1 = (ushort*)&o1; ushort* b2 = (ushort*)&o2;
#pragma unroll
                    for (int k = 0; k < 8; k++) {
                        float cs = tf[2 * k], sn = tf[2 * k + 1];
                        float x1 = bf2f(a1[k]), x2 = bf2f(a2[k]);
                        b1[k] = f2bf(x1 * cs - x2 * sn);
                        b2[k] = f2bf(x1 * sn + x2 * cs);
                    }
                    *(uint4*)p1 = o1; *(uint4*)p2 = o2;
                }
            }
        }
        BARL;     // rotated Q visible block-wide

        float m_r = NEGINF, l_r = 0.f;
        f32x16 oacc[6] = {};

        for (int kb = 0; kb < nkb; kb++) {
            const char* kc = Kb0 + (size_t)kb * 196608;   // +kb*128 k-rows
            const char* vc = Vb0 + (size_t)kb * 256;      // +kb*128 k-cols (bytes)
            const bool nx = (kb + 1 < nkb);
            const bool nm = (kb * 128 + 127 > q0);        // masking needed (vs qg_min)

            // ---- QK^T: 6 d-chunk phases ----
            f32x16 sacc = {};
#pragma unroll
            for (int c = 0; c < 6; c++) {
                PHASEB;                                    // chunk c landed; prev slot free
                if (c < 5) {
#pragma unroll
                    for (int r = 0; r < 4; r++)            // K_{c+1} -> slot (c+1)&1
                        gload16(kc + (c + 1) * 256 + (size_t)r * 49152,
                                pool + ((c + 1) & 1) * 32768 + r * 8192 + wid * 1024);
                } else {
#pragma unroll
                    for (int r = 0; r < 4; r++)            // V0 -> slot0
                        gload16(vc + (size_t)r * 131072, pool + r * 8192 + wid * 1024);
                }
                const char* kbuf = pool + (c & 1) * 32768;
                const char* qcb = Qs + c * 16384;
                __builtin_amdgcn_s_setprio(1);
#pragma unroll
                for (int s = 0; s < 8; s++) {
                    bf16x8 a = *(const bf16x8*)(kbuf + arow * 256 + ((s * 32 + hi16) ^ asw));
                    bf16x8 bq = *(const bf16x8*)(qcb + qrow * 256 + ((s * 32 + hi16) ^ qsw));
                    sacc = __builtin_amdgcn_mfma_f32_32x32x16_bf16(a, bq, sacc, 0, 0, 0);
                }
                __builtin_amdgcn_s_setprio(0);
            }

            BARL;   // K5 reads drained + fenced: slot1 -> P/stats overlay now safe

            // ---- pass 1: lane-local masked max ----
            const int kbase_ = kb * 128 + g * 32 + 4 * hi;
            float mloc = NEGINF;
            if (nm) {
#pragma unroll
                for (int r = 0; r < 16; r++) {
                    int kg = kbase_ + (r & 3) + 8 * (r >> 2);
                    if (kg <= qg) mloc = fmaxf(mloc, sacc[r]);
                }
            } else {
#pragma unroll
                for (int r = 0; r < 16; r++) mloc = fmaxf(mloc, sacc[r]);
            }
            mloc = fmaxf(mloc, __shfl_xor(mloc, 32));
            if (hi == 0) pmax_s[qrow * 4 + g] = mloc;
            BARL;

            // ---- pass 2: m_new; exps ONCE (feed P and psum); P -> LDS ----
            float4 pm = *(const float4*)&pmax_s[qrow * 4];
            float m_new = fmaxf(fmaxf(fmaxf(pm.x, pm.y), fmaxf(pm.z, pm.w)), m_r);
            float rv = __expf(m_r - m_new);
            float ps = 0.f; uint w[8];
            if (nm) {
#pragma unroll
                for (int j = 0; j < 8; j++) {
                    int kg0 = kbase_ + ((2 * j) & 3) + 8 * ((2 * j) >> 2);
                    int kg1 = kbase_ + ((2 * j + 1) & 3) + 8 * ((2 * j + 1) >> 2);
                    float e0 = (kg0 > qg) ? 0.f : __expf(sacc[2 * j] - m_new);
                    float e1 = (kg1 > qg) ? 0.f : __expf(sacc[2 * j + 1] - m_new);
                    ps += e0 + e1;
                    w[j] = (uint)f2bf(e0) | ((uint)f2bf(e1) << 16);
                }
            } else {
#pragma unroll
                for (int j = 0; j < 8; j++) {
                    float e0 = __expf(sacc[2 * j] - m_new);
                    float e1 = __expf(sacc[2 * j + 1] - m_new);
                    ps += e0 + e1;
                    w[j] = (uint)f2bf(e0) | ((uint)f2bf(e1) << 16);
                }
            }
            ps += __shfl_xor(ps, 32);
            if (hi == 0) psum_s[qrow * 4 + g] = ps;
#pragma unroll
            for (int j = 0; j < 4; j++) {
                uint2 pw; pw.x = w[2 * j]; pw.y = w[2 * j + 1];
                *(uint2*)(Pb + qrow * 256 + ((g * 64 + j * 16 + hi * 8) ^ qsw)) = pw;
            }
            BARL;

            // ---- pass 3: l update; rescale O (shfl rv); hoist P fragments ----
            float4 ps4 = *(const float4*)&psum_s[qrow * 4];
            l_r = l_r * rv + (ps4.x + ps4.y + ps4.z + ps4.w);
            m_r = m_new;
            float rs[16];
#pragma unroll
            for (int r = 0; r < 16; r++)
                rs[r] = __shfl(rv, (r & 3) + 8 * (r >> 2) + 4 * hi);
#pragma unroll
            for (int c = 0; c < 6; c++)
#pragma unroll
                for (int r = 0; r < 16; r++) oacc[c][r] *= rs[r];
            bf16x8 pa[8];
#pragma unroll
            for (int s = 0; s < 8; s++)
                pa[s] = *(const bf16x8*)(Pb + qrow * 256 + ((s * 32 + hi16) ^ qsw));

            // ---- PV: 6 dd-chunk phases ----
#pragma unroll
            for (int c = 0; c < 6; c++) {
                PHASEB;   // V_c landed; c==0: certifies pass-3 pa/psum reads done block-wide
                if (c < 5) {
#pragma unroll
                    for (int r = 0; r < 4; r++)            // V_{c+1} -> slot (c+1)&1
                        gload16(vc + (size_t)(c + 1) * 524288 + (size_t)r * 131072,
                                pool + ((c + 1) & 1) * 32768 + r * 8192 + wid * 1024);
                } else if (nx) {
#pragma unroll
                    for (int r = 0; r < 4; r++)            // next-iter K0 -> slot0
                        gload16(kc + 196608 + (size_t)r * 49152, pool + r * 8192 + wid * 1024);
                }
                const char* vbuf = pool + (c & 1) * 32768;
                __builtin_amdgcn_s_setprio(1);
#pragma unroll
                for (int s = 0; s < 8; s++) {
                    bf16x8 bv = *(const bf16x8*)(vbuf + arow * 256 + ((s * 32 + hi16) ^ asw));
                    oacc[c] = __builtin_amdgcn_mfma_f32_32x32x16_bf16(pa[s], bv, oacc[c], 0, 0, 0);
                }
                __builtin_amdgcn_s_setprio(0);
            }
        }

        // ---- epilogue: 1/l via shfl, write per-head output over Qr rows ----
        float inv16[16];
#pragma unroll
        for (int r = 0; r < 16; r++)
            inv16[r] = 1.0f / __shfl(l_r, (r & 3) + 8 * (r >> 2) + 4 * hi);
        ushort* obase = Oh + ((size_t)(bh * 2048 + q0 + qh * 32)) * 768;
#pragma unroll
        for (int c = 0; c < 6; c++) {
            int dd = c * 128 + g * 32 + l31;
#pragma unroll
            for (int r = 0; r < 16; r++) {
                int rq = (r & 3) + 8 * (r >> 2) + 4 * hi;
                obase[(size_t)rq * 768 + dd] = f2bf(oacc[c][r] * inv16[r]);
            }
        }
        // next tile's prologue PHASEB (vmcnt+lgkm+barrier) fences Qs/slot reuse
    }
}

// ---------------- head-sum reduce: out[b][t][d] = sum_h Oh[b][h][t][d] ----------------
__global__ void k_reduce(const ushort* __restrict__ Oh, float* __restrict__ out) {
    int i = blockIdx.x * blockDim.x + threadIdx.x;
    if (i >= 786432) return;                 // 2*2048*768/4
    size_t base = (size_t)i * 4;
    int b = (base >= 1572864) ? 1 : 0;       // 2048*768 = 1572864
    size_t rem = base - (size_t)b * 1572864;
    const ushort* src = Oh + (size_t)b * 8 * 1572864 + rem;
    float4 acc = {0.f, 0.f, 0.f, 0.f};
#pragma unroll
    for (int h = 0; h < 8; h++) {
        ushort4 v = *(const ushort4*)(src + (size_t)h * 1572864);
        acc.x += bf2f(v.x); acc.y += bf2f(v.y); acc.z += bf2f(v.z); acc.w += bf2f(v.w);
    }
    *(float4*)&out[base] = acc;
}

extern "C" void kernel_launch(void* const* d_in, const int* in_sizes, int n_in,
                              void* d_out, int out_size, void* d_ws, size_t ws_size,
                              hipStream_t stream) {
    const float* x = (const float*)d_in[0];
    const float* M = (const float*)d_in[1];
    const float* V = (const float*)d_in[2];
    const int* pos = (const int*)d_in[3];
    float* out = (float*)d_out;
    char* ws = (char*)d_ws;

    // workspace layout (bytes)
    ushort* xb   = (ushort*)(ws);                 //  6,291,456  x bf16 [4096][768]; later RoPE table
    ushort* Mt   = (ushort*)(ws + 6291456);       //  9,437,184  M^T bf16 [6144][768]
    ushort* Vt   = (ushort*)(ws + 15728640);      //  9,437,184  V^T bf16 [6144][768]
    ushort* Qr   = (ushort*)(ws + 25165824);      // 50,331,648  Q bf16 [b][h][t][768] (later Oh)
    ushort* valT = (ushort*)(ws + 75497472);      // 50,331,648  val^T bf16 [b][h][dd][t]
    ushort* Kr   = (ushort*)(ws + 125829120);     //  6,291,456  K bf16 [b][t][768]
    float2* tab  = (float2*)(ws);                 //  6,291,456  (cos,sin)*SCALE [2048][384] — overwrites xb

    k_convx<<<3072, 256, 0, stream>>>(x, xb, 786432);
    k_tconv2<<<dim3(24, 192, 2), 256, 0, stream>>>(M, V, Mt, Vt);
    k_gemmc<<<dim3(1536, 1, 2), 256, 0, stream>>>(xb, Mt, Vt, Qr, valT);
    k_ropek<<<1536, 256, 0, stream>>>(x, Kr, pos, tab, 4096);   // tab safely overwrites xb (after GEMMs)
    k_attn<<<dim3(16, 8, 2), 512, 0, stream>>>(Qr, Kr, valT, tab, Qr /*Oh overwrites Qr*/);
    k_reduce<<<3072, 256, 0, stream>>>(Qr, out);
}

// Round 17
// 345.908 us; speedup vs baseline: 1.0395x; 1.0395x over previous
//
#include <hip/hip_runtime.h>
#include <hip/hip_bf16.h>

typedef __bf16 bf16x8 __attribute__((ext_vector_type(8)));
typedef float f32x4 __attribute__((ext_vector_type(4)));
typedef float f32x16 __attribute__((ext_vector_type(16)));

// B=2, T=2048, d=768, h=8
#define SCALE 0.03608439182435161f   // 1/sqrt(768)
#define NEGINF (-1e30f)

static __device__ __forceinline__ ushort f2bf(float f) {
    union { float f; unsigned u; } v; v.f = f;
    unsigned r = (v.u + 0x7fff + ((v.u >> 16) & 1)) >> 16;  // RTE
    return (ushort)r;
}
static __device__ __forceinline__ float bf2f(ushort u) {
    union { unsigned u; float f; } v; v.u = ((unsigned)u) << 16;
    return v.f;
}

// async 16B global -> LDS (dest: wave-uniform base + lane*16)
static __device__ __forceinline__ void gload16(const void* g, void* lds) {
    __builtin_amdgcn_global_load_lds((const __attribute__((address_space(1))) void*)g,
                                     (__attribute__((address_space(3))) void*)lds, 16, 0, 0);
}

// ALL barriers fenced: raw s_barrier is NOT a compiler memory fence (R9 lesson).
#define PHASEB do { asm volatile("s_waitcnt vmcnt(0) lgkmcnt(0)" ::: "memory"); \
                    __builtin_amdgcn_s_barrier(); \
                    asm volatile("" ::: "memory"); } while (0)
#define BARL do { asm volatile("s_waitcnt lgkmcnt(0)" ::: "memory"); \
                  __builtin_amdgcn_s_barrier(); \
                  asm volatile("" ::: "memory"); } while (0)

// ---------------- f32 -> bf16 convert (x) ----------------
__global__ void k_convx(const float* __restrict__ x, ushort* __restrict__ xb, int n4) {
    int i = blockIdx.x * blockDim.x + threadIdx.x;
    if (i >= n4) return;
    float4 v = ((const float4*)x)[i];
    ushort4 o; o.x = f2bf(v.x); o.y = f2bf(v.y); o.z = f2bf(v.z); o.w = f2bf(v.w);
    ((ushort4*)xb)[i] = o;
}

// ---------------- f32 [R][C] -> bf16 [C][R] transpose-convert ----------------
__global__ void k_tconv(const float* __restrict__ in, ushort* __restrict__ out, int R, int C) {
    __shared__ float ts[32][33];
    int r0 = blockIdx.x * 32, c0 = blockIdx.y * 32;
    int lr = threadIdx.x >> 5, lc = threadIdx.x & 31;
#pragma unroll
    for (int i = 0; i < 4; i++) ts[lr + i * 8][lc] = in[(r0 + lr + i * 8) * C + c0 + lc];
    __syncthreads();
#pragma unroll
    for (int i = 0; i < 4; i++) out[(c0 + lr + i * 8) * R + r0 + lc] = f2bf(ts[lc][lr + i * 8]);
}

// ---------------- bf16 GEMM (m97-style): C[M][N] = A[M][768] * Bt[N][768]^T ----------------
template <int EPI>
__global__ __launch_bounds__(256) void k_gemm(const ushort* __restrict__ A,
                                              const ushort* __restrict__ Bt,
                                              ushort* __restrict__ out) {
    __shared__ ushort As[128 * 32];
    __shared__ ushort Bs[128 * 32];
    const int m0 = blockIdx.x * 128, n0 = blockIdx.y * 128;
    const int tid = threadIdx.x, lane = tid & 63, wid = tid >> 6;
    const int wm = (wid >> 1) * 64, wn = (wid & 1) * 64;
    const int l15 = lane & 15, l4 = lane >> 4;
    const int srow = tid >> 2, scol = (tid & 3) * 8;
    f32x4 acc[4][4] = {};

    for (int kt = 0; kt < 768; kt += 32) {
        gload16(&A[(size_t)(m0 + srow) * 768 + kt + scol],       (char*)As + wid * 1024);
        gload16(&A[(size_t)(m0 + 64 + srow) * 768 + kt + scol],  (char*)As + 4096 + wid * 1024);
        gload16(&Bt[(size_t)(n0 + srow) * 768 + kt + scol],      (char*)Bs + wid * 1024);
        gload16(&Bt[(size_t)(n0 + 64 + srow) * 768 + kt + scol], (char*)Bs + 4096 + wid * 1024);
        PHASEB;
        bf16x8 af[4], bfr[4];
#pragma unroll
        for (int m = 0; m < 4; m++)
            af[m] = *(const bf16x8*)&As[(wm + m * 16 + l15) * 32 + l4 * 8];
#pragma unroll
        for (int n = 0; n < 4; n++)
            bfr[n] = *(const bf16x8*)&Bs[(wn + n * 16 + l15) * 32 + l4 * 8];
#pragma unroll
        for (int m = 0; m < 4; m++)
#pragma unroll
            for (int n = 0; n < 4; n++)
                acc[m][n] = __builtin_amdgcn_mfma_f32_16x16x32_bf16(af[m], bfr[n], acc[m][n], 0, 0, 0);
        BARL;
    }

#pragma unroll
    for (int m = 0; m < 4; m++) {
#pragma unroll
        for (int n = 0; n < 4; n++) {
#pragma unroll
            for (int r = 0; r < 4; r++) {
                int row = m0 + wm + m * 16 + (lane >> 4) * 4 + r;
                int col = n0 + wn + n * 16 + (lane & 15);
                float v = acc[m][n][r];
                int idx;
                if (EPI == 0) {
                    int b = row >> 11, t = row & 2047;
                    int hh = col / 768, dd = col - hh * 768;
                    idx = ((b * 8 + hh) * 2048 + t) * 768 + dd;
                } else {
                    int hh = row / 768, dd = row - hh * 768;
                    int b = col >> 11, t = col & 2047;
                    idx = ((b * 8 + hh) * 768 + dd) * 2048 + t;
                }
                out[idx] = f2bf(v);
            }
        }
    }
}

// ---------------- RoPE(x) -> Kr bf16 (layout [b][t][768]); also emits cos/sin table ----------------
// tab[t][j] = (cos(ang)*SCALE, sin(ang)*SCALE), j in [0,384), written by b==0 rows.
__global__ void k_ropek(const float* __restrict__ x, ushort* __restrict__ Kr,
                        const int* __restrict__ pos, float2* __restrict__ tab, int nrows) {
    int i = blockIdx.x * blockDim.x + threadIdx.x;
    int row = i / 96, j4 = (i % 96) * 4;
    if (row >= nrows) return;
    float p = (float)pos[row & 2047];
    float4 x1 = *(const float4*)&x[row * 768 + j4];
    float4 x2 = *(const float4*)&x[row * 768 + 384 + j4];
    ushort4 o1, o2;
    float a1[4] = {x1.x, x1.y, x1.z, x1.w};
    float a2[4] = {x2.x, x2.y, x2.z, x2.w};
#pragma unroll
    for (int k = 0; k < 4; k++) {
        float inv = exp2f(-(float)(j4 + k) * (13.287712379549449f / 384.0f));
        float ang = p * inv;
        float s, c; sincosf(ang, &s, &c);
        ((ushort*)&o1)[k] = f2bf(a1[k] * c - a2[k] * s);
        ((ushort*)&o2)[k] = f2bf(a1[k] * s + a2[k] * c);
        if (row < 2048) tab[(size_t)row * 384 + j4 + k] = make_float2(c * SCALE, s * SCALE);
    }
    *(ushort4*)&Kr[row * 768 + j4] = o1;
    *(ushort4*)&Kr[row * 768 + 384 + j4] = o2;
}

// ---------------- Flash attention v14: table-RoPE on Q + 17-exp/2-barrier softmax ----------------
// QBLK=64, KBLK=128, 512 threads (8 waves: g=k-tile x qh=q-half), 1 block/CU.
__global__ __launch_bounds__(512, 2) void k_attn(const ushort* Qr, const ushort* __restrict__ Kr,
                                                 const ushort* __restrict__ valT,
                                                 const float2* __restrict__ tab, ushort* Oh) {
    __shared__ alignas(128) char Qs[98304];     // [6][64 q][128 d] bf16, 16-deep XOR swizzle
    __shared__ alignas(128) char pool[65536];   // 2 x 32KB stream slots

    const int p = blockIdx.x, hh = blockIdx.y, b = blockIdx.z;
    const int bh = b * 8 + hh;
    const int tid = threadIdx.x, lane = tid & 63, wid = tid >> 6;
    const int g = wid & 3, qh = wid >> 2;       // k-tile / q-half roles
    const int l31 = lane & 31, hi = lane >> 5;
    const int hi16 = hi << 4;

    // staging geometry: chunk = [128 rows][256B], dest linear = tid*16 per 8KB round
    const int row0 = tid >> 4, col16 = tid & 15;
    const int swz = (col16 << 4) ^ ((row0 & 15) << 4);   // pre-swizzled source column

    const int arow = g * 32 + l31;              // K row (QK A) / V dd-row (PV B)
    const int qrow = qh * 32 + l31;             // Q row (QK B) / lane's q
    const int asw = (arow & 15) << 4;
    const int qsw = (qrow & 15) << 4;

    char* Pb = pool + 32768;                    // P [64 q][128 k] bf16 (slot1 overlay)
    float* pmax_s = (float*)(pool + 49152);     // [64][4] — disjoint from P
    float* psum_s = (float*)(pool + 50176);     // [64][4]

    const char* Kb0 = (const char*)Kr + ((size_t)(b * 2048 + row0)) * 1536 + swz;
    const char* Vb0 = (const char*)valT + ((size_t)(bh * 768 + row0)) * 4096 + swz;

    for (int ti = 0; ti < 2; ti++) {
        const int qt = ti ? (31 - p) : p;
        const int q0 = qt * 64;
        const int nkb = (qt + 2) >> 1;
        const int qg = q0 + qrow;

        // prologue: issue Q (6 chunks, 12 rounds) + K0 -> slot0
        const char* qsrc = (const char*)Qr + ((size_t)(bh * 2048 + q0 + row0)) * 1536 + swz;
#pragma unroll
        for (int r = 0; r < 12; r++)
            gload16(qsrc + (r >> 1) * 256 + (size_t)(r & 1) * 49152,
                    Qs + (r >> 1) * 16384 + (r & 1) * 8192 + wid * 1024);
#pragma unroll
        for (int r = 0; r < 4; r++)
            gload16(Kb0 + (size_t)r * 49152, pool + r * 8192 + wid * 1024);

        PHASEB;   // Q (and K0) landed block-wide

        // ---- fused RoPE+SCALE on Q, in LDS (table-based) ----
        // pair (d, d+384) lives in chunks (c, c+3) at the same row/byte offset.
        {
            const int rr = tid >> 3;                 // 0..63 (q row in tile)
            const int gb0 = (tid & 7) * 16;          // granule byte base
            const int rsw = (rr & 15) << 4;
            const float2* trow = tab + (size_t)(q0 + rr) * 384 + (gb0 >> 1);
#pragma unroll
            for (int c = 0; c < 3; c++) {
#pragma unroll
                for (int h2 = 0; h2 < 2; h2++) {
                    int gb = gb0 + h2 * 128;
                    char* p1 = Qs + c * 16384 + rr * 256 + (gb ^ rsw);
                    char* p2 = Qs + (c + 3) * 16384 + rr * 256 + (gb ^ rsw);
                    uint4 u1 = *(uint4*)p1, u2 = *(uint4*)p2;
                    const float4* tp = (const float4*)(trow + c * 128 + h2 * 64);
                    float4 T0 = tp[0], T1 = tp[1], T2 = tp[2], T3 = tp[3];
                    const float tf[16] = {T0.x, T0.y, T0.z, T0.w, T1.x, T1.y, T1.z, T1.w,
                                          T2.x, T2.y, T2.z, T2.w, T3.x, T3.y, T3.z, T3.w};
                    uint4 o1, o2;
                    ushort* a1 = (ushort*)&u1; ushort* a2 = (ushort*)&u2;
                    ushort* b1 = (ushort*)&o1; ushort* b2 = (ushort*)&o2;
#pragma unroll
                    for (int k = 0; k < 8; k++) {
                        float cs = tf[2 * k], sn = tf[2 * k + 1];
                        float x1 = bf2f(a1[k]), x2 = bf2f(a2[k]);
                        b1[k] = f2bf(x1 * cs - x2 * sn);
                        b2[k] = f2bf(x1 * sn + x2 * cs);
                    }
                    *(uint4*)p1 = o1; *(uint4*)p2 = o2;
                }
            }
        }
        BARL;     // rotated Q visible block-wide

        float m_r = NEGINF, l_r = 0.f;
        f32x16 oacc[6] = {};

        for (int kb = 0; kb < nkb; kb++) {
            const char* kc = Kb0 + (size_t)kb * 196608;   // +kb*128 k-rows
            const char* vc = Vb0 + (size_t)kb * 256;      // +kb*128 k-cols (bytes)
            const bool nx = (kb + 1 < nkb);
            const bool nm = (kb * 128 + 127 > q0);        // masking needed (vs qg_min)

            // ---- QK^T: 6 d-chunk phases ----
            f32x16 sacc = {};
#pragma unroll
            for (int c = 0; c < 6; c++) {
                PHASEB;                                    // chunk c landed; prev slot free
                if (c < 5) {
#pragma unroll
                    for (int r = 0; r < 4; r++)            // K_{c+1} -> slot (c+1)&1
                        gload16(kc + (c + 1) * 256 + (size_t)r * 49152,
                                pool + ((c + 1) & 1) * 32768 + r * 8192 + wid * 1024);
                } else {
#pragma unroll
                    for (int r = 0; r < 4; r++)            // V0 -> slot0
                        gload16(vc + (size_t)r * 131072, pool + r * 8192 + wid * 1024);
                }
                const char* kbuf = pool + (c & 1) * 32768;
                const char* qcb = Qs + c * 16384;
                __builtin_amdgcn_s_setprio(1);
#pragma unroll
                for (int s = 0; s < 8; s++) {
                    bf16x8 a = *(const bf16x8*)(kbuf + arow * 256 + ((s * 32 + hi16) ^ asw));
                    bf16x8 bq = *(const bf16x8*)(qcb + qrow * 256 + ((s * 32 + hi16) ^ qsw));
                    sacc = __builtin_amdgcn_mfma_f32_32x32x16_bf16(a, bq, sacc, 0, 0, 0);
                }
                __builtin_amdgcn_s_setprio(0);
            }

            BARL;   // K5 reads drained + fenced: slot1 -> P/stats overlay now safe

            // ---- pass 1: lane-local masked max ----
            const int kbase_ = kb * 128 + g * 32 + 4 * hi;
            float mloc = NEGINF;
            if (nm) {
#pragma unroll
                for (int r = 0; r < 16; r++) {
                    int kg = kbase_ + (r & 3) + 8 * (r >> 2);
                    if (kg <= qg) mloc = fmaxf(mloc, sacc[r]);
                }
            } else {
#pragma unroll
                for (int r = 0; r < 16; r++) mloc = fmaxf(mloc, sacc[r]);
            }
            mloc = fmaxf(mloc, __shfl_xor(mloc, 32));
            if (hi == 0) pmax_s[qrow * 4 + g] = mloc;
            BARL;

            // ---- pass 2: m_new; exps ONCE (feed P and psum); P -> LDS ----
            float4 pm = *(const float4*)&pmax_s[qrow * 4];
            float m_new = fmaxf(fmaxf(fmaxf(pm.x, pm.y), fmaxf(pm.z, pm.w)), m_r);
            float rv = __expf(m_r - m_new);
            float ps = 0.f; uint w[8];
            if (nm) {
#pragma unroll
                for (int j = 0; j < 8; j++) {
                    int kg0 = kbase_ + ((2 * j) & 3) + 8 * ((2 * j) >> 2);
                    int kg1 = kbase_ + ((2 * j + 1) & 3) + 8 * ((2 * j + 1) >> 2);
                    float e0 = (kg0 > qg) ? 0.f : __expf(sacc[2 * j] - m_new);
                    float e1 = (kg1 > qg) ? 0.f : __expf(sacc[2 * j + 1] - m_new);
                    ps += e0 + e1;
                    w[j] = (uint)f2bf(e0) | ((uint)f2bf(e1) << 16);
                }
            } else {
#pragma unroll
                for (int j = 0; j < 8; j++) {
                    float e0 = __expf(sacc[2 * j] - m_new);
                    float e1 = __expf(sacc[2 * j + 1] - m_new);
                    ps += e0 + e1;
                    w[j] = (uint)f2bf(e0) | ((uint)f2bf(e1) << 16);
                }
            }
            ps += __shfl_xor(ps, 32);
            if (hi == 0) psum_s[qrow * 4 + g] = ps;
#pragma unroll
            for (int j = 0; j < 4; j++) {
                uint2 pw; pw.x = w[2 * j]; pw.y = w[2 * j + 1];
                *(uint2*)(Pb + qrow * 256 + ((g * 64 + j * 16 + hi * 8) ^ qsw)) = pw;
            }
            BARL;

            // ---- pass 3: l update; rescale O (shfl rv); hoist P fragments ----
            float4 ps4 = *(const float4*)&psum_s[qrow * 4];
            l_r = l_r * rv + (ps4.x + ps4.y + ps4.z + ps4.w);
            m_r = m_new;
            float rs[16];
#pragma unroll
            for (int r = 0; r < 16; r++)
                rs[r] = __shfl(rv, (r & 3) + 8 * (r >> 2) + 4 * hi);
#pragma unroll
            for (int c = 0; c < 6; c++)
#pragma unroll
                for (int r = 0; r < 16; r++) oacc[c][r] *= rs[r];
            bf16x8 pa[8];
#pragma unroll
            for (int s = 0; s < 8; s++)
                pa[s] = *(const bf16x8*)(Pb + qrow * 256 + ((s * 32 + hi16) ^ qsw));

            // ---- PV: 6 dd-chunk phases ----
#pragma unroll
            for (int c = 0; c < 6; c++) {
                PHASEB;   // V_c landed; c==0: certifies pass-3 pa/psum reads done block-wide
                if (c < 5) {
#pragma unroll
                    for (int r = 0; r < 4; r++)            // V_{c+1} -> slot (c+1)&1
                        gload16(vc + (size_t)(c + 1) * 524288 + (size_t)r * 131072,
                                pool + ((c + 1) & 1) * 32768 + r * 8192 + wid * 1024);
                } else if (nx) {
#pragma unroll
                    for (int r = 0; r < 4; r++)            // next-iter K0 -> slot0
                        gload16(kc + 196608 + (size_t)r * 49152, pool + r * 8192 + wid * 1024);
                }
                const char* vbuf = pool + (c & 1) * 32768;
                __builtin_amdgcn_s_setprio(1);
#pragma unroll
                for (int s = 0; s < 8; s++) {
                    bf16x8 bv = *(const bf16x8*)(vbuf + arow * 256 + ((s * 32 + hi16) ^ asw));
                    oacc[c] = __builtin_amdgcn_mfma_f32_32x32x16_bf16(pa[s], bv, oacc[c], 0, 0, 0);
                }
                __builtin_amdgcn_s_setprio(0);
            }
        }

        // ---- epilogue: 1/l via shfl, write per-head output over Qr rows ----
        float inv16[16];
#pragma unroll
        for (int r = 0; r < 16; r++)
            inv16[r] = 1.0f / __shfl(l_r, (r & 3) + 8 * (r >> 2) + 4 * hi);
        ushort* obase = Oh + ((size_t)(bh * 2048 + q0 + qh * 32)) * 768;
#pragma unroll
        for (int c = 0; c < 6; c++) {
            int dd = c * 128 + g * 32 + l31;
#pragma unroll
            for (int r = 0; r < 16; r++) {
                int rq = (r & 3) + 8 * (r >> 2) + 4 * hi;
                obase[(size_t)rq * 768 + dd] = f2bf(oacc[c][r] * inv16[r]);
            }
        }
        // next tile's prologue PHASEB (vmcnt+lgkm+barrier) fences Qs/slot reuse
    }
}

// ---------------- head-sum reduce: out[b][t][d] = sum_h Oh[b][h][t][d] ----------------
__global__ void k_reduce(const ushort* __restrict__ Oh, float* __restrict__ out) {
    int i = blockIdx.x * blockDim.x + threadIdx.x;
    if (i >= 786432) return;                 // 2*2048*768/4
    size_t base = (size_t)i * 4;
    int b = (base >= 1572864) ? 1 : 0;       // 2048*768 = 1572864
    size_t rem = base - (size_t)b * 1572864;
    const ushort* src = Oh + (size_t)b * 8 * 1572864 + rem;
    float4 acc = {0.f, 0.f, 0.f, 0.f};
#pragma unroll
    for (int h = 0; h < 8; h++) {
        ushort4 v = *(const ushort4*)(src + (size_t)h * 1572864);
        acc.x += bf2f(v.x); acc.y += bf2f(v.y); acc.z += bf2f(v.z); acc.w += bf2f(v.w);
    }
    *(float4*)&out[base] = acc;
}

extern "C" void kernel_launch(void* const* d_in, const int* in_sizes, int n_in,
                              void* d_out, int out_size, void* d_ws, size_t ws_size,
                              hipStream_t stream) {
    const float* x = (const float*)d_in[0];
    const float* M = (const float*)d_in[1];
    const float* V = (const float*)d_in[2];
    const int* pos = (const int*)d_in[3];
    float* out = (float*)d_out;
    char* ws = (char*)d_ws;

    // workspace layout (bytes)
    ushort* xb   = (ushort*)(ws);                 //  6,291,456  x bf16 [4096][768]; later RoPE table
    ushort* Mt   = (ushort*)(ws + 6291456);       //  9,437,184  M^T bf16 [6144][768]
    ushort* Vt   = (ushort*)(ws + 15728640);      //  9,437,184  V^T bf16 [6144][768]
    ushort* Qr   = (ushort*)(ws + 25165824);      // 50,331,648  Q bf16 [b][h][t][768] (later Oh)
    ushort* valT = (ushort*)(ws + 75497472);      // 50,331,648  val^T bf16 [b][h][dd][t]
    ushort* Kr   = (ushort*)(ws + 125829120);     //  6,291,456  K bf16 [b][t][768]
    float2* tab  = (float2*)(ws);                 //  6,291,456  (cos,sin)*SCALE [2048][384] — overwrites xb

    k_convx<<<3072, 256, 0, stream>>>(x, xb, 786432);
    k_tconv<<<dim3(24, 192), 256, 0, stream>>>(M, Mt, 768, 6144);
    k_tconv<<<dim3(24, 192), 256, 0, stream>>>(V, Vt, 768, 6144);
    k_gemm<0><<<dim3(32, 48), 256, 0, stream>>>(xb, Mt, Qr);
    k_gemm<1><<<dim3(48, 32), 256, 0, stream>>>(Vt, xb, valT);
    k_ropek<<<1536, 256, 0, stream>>>(x, Kr, pos, tab, 4096);   // tab safely overwrites xb (after GEMMs)
    k_attn<<<dim3(16, 8, 2), 512, 0, stream>>>(Qr, Kr, valT, tab, Qr /*Oh overwrites Qr*/);
    k_reduce<<<3072, 256, 0, stream>>>(Qr, out);
}